// Round 14
// baseline (119.292 us; speedup 1.0000x reference)
//
#include <hip/hip_runtime.h>
#include <hip/hip_bf16.h>

// Problem constants
#define BATCH 32
#define LTOT 4096
#define CCH 64
#define NFFT 16
#define HOP 4
#define NF 9            // n_fft/2+1
#define T_FR 1025       // 1 + L/HOP
#define T_ROWS 1032     // padded rows in mag workspace (rows >= 1025 zeroed)
#define ICH 576         // C * NF
#define OCH 512
#define TY 1023         // conv output length
#define OUTW 128
#define KTOT 1728       // 3 taps x 576

typedef __attribute__((ext_vector_type(8))) _Float16 half8;
typedef __attribute__((ext_vector_type(4))) float floatx4;

// cos(n*pi/8) for n = 0..15 — used only for the window now.
__device__ constexpr float C16[16] = {
    1.0f,  0.923879533f,  0.707106781f,  0.382683432f,  0.0f, -0.382683432f,
   -0.707106781f, -0.923879533f, -1.0f, -0.923879533f, -0.707106781f,
   -0.382683432f,  0.0f,  0.382683432f,  0.707106781f,  0.923879533f};

#define C1F 0.923879533f   // cos(pi/8)
#define C2F 0.707106781f   // cos(2pi/8)
#define C3F 0.382683432f   // cos(3pi/8) = sin(pi/8)

__device__ __forceinline__ void async_copy16(const _Float16* g, _Float16* l) {
  __builtin_amdgcn_global_load_lds(
      (const __attribute__((address_space(1))) unsigned int*)g,
      (__attribute__((address_space(3))) unsigned int*)l, 16, 0, 0);
}

// R24: raw v_sqrt_f32 (~1 ulp).  sqrtf() without -ffast-math is a ~25-op
// guarded sequence.
__device__ __forceinline__ float fsqrt_fast(float v) {
  float r;
  asm("v_sqrt_f32 %0, %1" : "=v"(r) : "v"(v));
  return r;
}

// raw barrier + counted vmcnt (no compiler-inserted vmcnt(0) drain)
#define SBAR() asm volatile("s_barrier" ::: "memory")
#define WAITV(N) asm volatile("s_waitcnt vmcnt(" #N ")" ::: "memory")

// ---------------------------------------------------------------------------
// Kernel 1 (R28 = R19 structure + R26 factored DFT): STFT magnitude +
// weight repack.  x [B,L,C] fp32 -> m_ws [b][t][f*64+c] fp16.
// R27 post-mortem: the FUSED stft+pool ran at ~3.5x its VALU-issue bound —
// its fixed per-block structure (4 barrier phases, LDS reduction, divergent
// epilogue, 1.37x row recompute) dominated once the DFT ops were cut.  The
// split R19 structure measured only ~1.4x issue-bound (one thread = one
// t-row end-to-end, no reduction, full-width stores).  So: un-fuse, keep
// the factored DFT (R26 identity ledger, f=8 fold EVEN: re8 = wxp+(Se-So))
// and fast sqrt.  m_ws round-trip costs ~11 us HBM but deletes ~25 us of
// fused-structure stalls.
// block 256 = 64 c x 4 t; grid (258 t-tiles, 32 b).
// ---------------------------------------------------------------------------
__global__ __launch_bounds__(256) void stft_wrepack_kernel(
    const float* __restrict__ x, const float* __restrict__ weight,
    _Float16* __restrict__ m_ws, _Float16* __restrict__ wkr) {
  const int b = blockIdx.y;
  const int t0 = blockIdx.x * 4;
  const int tid = threadIdx.x;

  // ---- weight repack slice (wkr[o][k*576 + f*64 + c], K contiguous) ----
  const int gid = (b * 258 + blockIdx.x) * 256 + tid;
  if (gid < OCH * ICH) {
    int o = gid / ICH, i = gid - o * ICH;
    int c = i / 9, f = i - c * 9;
    const float* src = weight + (size_t)o * (ICH * 3) + i * 3;
    _Float16* dst = wkr + (size_t)o * KTOT + f * 64 + c;
#pragma unroll
    for (int k = 0; k < 3; ++k)
      dst[k * ICH] = (_Float16)src[k];
  }

  // ---- stage x rows t0*4-8 .. +27 (reflect-padded), float4 ----
  __shared__ float xs[28 * 64];   // frames for 4 t: 4*4+12 = 28 rows
  const int l0 = t0 * HOP - 8;
  const float* xb = x + (size_t)b * LTOT * CCH;
#pragma unroll
  for (int it = 0; it < 2; ++it) {
    int e = it * 256 + tid;
    int r = e >> 4, c4 = e & 15;
    if (r < 28) {
      int l = l0 + r;
      if (l < 0) l = -l;
      if (l >= LTOT) l = 2 * LTOT - 2 - l;
      *(floatx4*)(&xs[r * 64 + c4 * 4]) =
          *(const floatx4*)(&xb[(size_t)l * CCH + c4 * 4]);
    }
  }
  __syncthreads();

  const int c = tid & 63, tq = tid >> 6;
  const int t = t0 + tq;    // t <= 1031 < T_ROWS
  _Float16* o_ptr = m_ws + ((size_t)b * T_ROWS + t) * ICH + c;
  if (t >= T_FR) {
#pragma unroll
    for (int f = 0; f < NF; ++f) o_ptr[f * 64] = (_Float16)0.0f;
    return;
  }

  float wx[16];
#pragma unroll
  for (int j = 0; j < 16; ++j)
    wx[j] = xs[(tq * 4 + j) * 64 + c] * (0.5f * (1.0f - C16[j]));
  // fold j <-> 16-j
  const float s1 = wx[1] + wx[15], d1 = wx[1] - wx[15];
  const float s2 = wx[2] + wx[14], d2 = wx[2] - wx[14];
  const float s3 = wx[3] + wx[13], d3 = wx[3] - wx[13];
  const float s4 = wx[4] + wx[12], d4 = wx[4] - wx[12];
  const float s5 = wx[5] + wx[11], d5 = wx[5] - wx[11];
  const float s6 = wx[6] + wx[10], d6 = wx[6] - wx[10];
  const float s7 = wx[7] + wx[9],  d7 = wx[7] - wx[9];
  const float wxp = wx[0] + wx[8], wxm = wx[0] - wx[8];
  // shared sums
  const float u1 = s2 - s6, u2 = s1 - s7, u3 = s3 - s5;
  const float v1 = d2 + d6, v2 = d1 + d7, v3 = d3 + d5;
  const float Se = s2 + s4 + s6;
  const float So = (s1 + s3) + (s5 + s7);
  // f = 0, 8: im == 0 (even fold both use wxp)
  const float re0 = wxp + Se + So;
  const float re8 = wxp + (Se - So);
  // pair (1,7) and (3,5) share products
  const float tA = C2F * u1;
  const float A1 = wxm + tA, A3 = wxm - tA;
  const float B1 = C1F * u2 + C3F * u3;
  const float B3 = C3F * u2 - C1F * u3;
  const float tP = C2F * v1;
  const float P1 = d4 + tP, P3 = tP - d4;
  const float Q1 = C3F * v2 + C1F * v3;
  const float Q3 = C1F * v2 - C3F * v3;
  // pair (2,6)
  const float A2 = wxp - s4;
  const float B2 = C2F * (((s1 - s3) - s5) + s7);
  const float P2 = d2 - d6;
  const float Q2 = C2F * (((d1 + d3) - d5) - d7);
  // f = 4
  const float re4 = ((wxp - s2) + s4) - s6;
  const float im4 = ((d1 - d3) + d5) - d7;

  o_ptr[0 * 64] = (_Float16)fabsf(re0);
  o_ptr[8 * 64] = (_Float16)fabsf(re8);
  {
    const float r1 = A1 + B1, i1 = P1 + Q1;
    o_ptr[1 * 64] = (_Float16)fsqrt_fast(r1 * r1 + i1 * i1);
    const float r7 = A1 - B1, i7 = Q1 - P1;
    o_ptr[7 * 64] = (_Float16)fsqrt_fast(r7 * r7 + i7 * i7);
    const float r2 = A2 + B2, i2 = P2 + Q2;
    o_ptr[2 * 64] = (_Float16)fsqrt_fast(r2 * r2 + i2 * i2);
    const float r6 = A2 - B2, i6 = Q2 - P2;
    o_ptr[6 * 64] = (_Float16)fsqrt_fast(r6 * r6 + i6 * i6);
    const float r3 = A3 + B3, i3 = P3 + Q3;
    o_ptr[3 * 64] = (_Float16)fsqrt_fast(r3 * r3 + i3 * i3);
    const float r5 = A3 - B3, i5 = Q3 - P3;
    o_ptr[5 * 64] = (_Float16)fsqrt_fast(r5 * r5 + i5 * i5);
    o_ptr[4 * 64] = (_Float16)fsqrt_fast(re4 * re4 + im4 * im4);
  }
}

// ---------------------------------------------------------------------------
// Kernel 2 (R22, unchanged): pre-pool the magnitudes (conv/pool commute).
// pmean[b][w][k*576+i] = (1/cnt_w) sum_{t in [s_w,e_w)} m[b][t+k][i]
// (t+k <= 1024 < T_FR; bins exactly match torch adaptive_avg_pool1d.)
// block 256 (216 active: 3 k x 72 i-octets), one block per (w, b).
// ---------------------------------------------------------------------------
__global__ __launch_bounds__(256) void pmean_kernel(
    const _Float16* __restrict__ m_ws, _Float16* __restrict__ pm) {
  const int w = blockIdx.x, b = blockIdx.y;
  const int j = threadIdx.x;
  if (j >= 216) return;
  const int k = j / 72;                  // tap 0..2
  const int i8 = (j - k * 72) * 8;       // i-octet base
  const int s = (w * TY) >> 7;
  const int e = ((w + 1) * TY + 127) >> 7;
  const int cnt = e - s;
  const float inv = 1.0f / (float)cnt;
  const _Float16* src =
      m_ws + ((size_t)b * T_ROWS + s + k) * ICH + i8;
  float acc[8];
#pragma unroll
  for (int q = 0; q < 8; ++q) acc[q] = 0.0f;
  for (int t = 0; t < cnt; ++t) {
    half8 v = *(const half8*)(src + (size_t)t * ICH);
#pragma unroll
    for (int q = 0; q < 8; ++q) acc[q] += (float)v[q];
  }
  half8 r;
#pragma unroll
  for (int q = 0; q < 8; ++q) r[q] = (_Float16)(acc[q] * inv);
  *(half8*)(pm + ((size_t)(b * OUTW + w)) * KTOT + j * 8) = r;
}

// ---------------------------------------------------------------------------
// Kernel 3 (R27, unchanged): the collapsed GEMM, double-buffered.
//   out[b][w][o] = bias[o] + sum_{kappa<1728} wkr[o][kappa]*pmean[b][w][kappa]
// as/bs double-buffered (48 KB), step k+1's 6 copies/wave issued BEFORE
// computing step k, raw s_barrier + counted vmcnt(6).
// Tile 64(o) x 128(w = one batch), grid 256 = 1 block/CU; proven R13
// fragment/staging swizzle.  XCD map: all 8 o-tiles of batch b on one XCD.
// ---------------------------------------------------------------------------
__global__ __launch_bounds__(256, 2) void gemm_pooled_kernel(
    const _Float16* __restrict__ pm, const _Float16* __restrict__ wkr,
    const float* __restrict__ bias, float* __restrict__ out) {
  const int lid = blockIdx.x;            // 0..255
  const int xcd = lid & 7;
  const int rest = lid >> 3;             // 0..31
  const int m8 = rest & 7;               // o-tile 0..7
  const int bq = rest >> 3;              // 0..3
  const int b = bq * 8 + xcd;
  const int o0 = m8 * 64;

  const int tid = threadIdx.x;
  const int wave = tid >> 6, lane = tid & 63;
  const int wm = wave >> 1, wn = wave & 1;   // 2(o) x 2(w) wave grid

  __shared__ _Float16 as[2][64 * 64];    // 2 x 8 KB  (W rows o0..o0+63)
  __shared__ _Float16 bs[2][128 * 64];   // 2 x 16 KB (pmean rows, all w of b)

  floatx4 acc[2][4];
#pragma unroll
  for (int mt = 0; mt < 2; ++mt)
#pragma unroll
    for (int nt = 0; nt < 4; ++nt)
      acc[mt][nt] = (floatx4)0.0f;

  const int frow = lane & 15;
  const int quad = lane >> 4;
  const int l7 = lane & 7;
  const int srow = lane >> 3;
  const int ssrc_off = srow * KTOT + (l7 ^ srow) * 8;

  const _Float16* ab = wkr + (size_t)o0 * KTOT;
  const _Float16* bb = pm + (size_t)b * OUTW * KTOT;

  // per-wave per-step vmem: 2 A copies then 4 B copies (FIFO, uniform)
#define GSTAGE(kbx, buf)                                                     \
  {                                                                          \
    const int i0s = (kbx) * 64;                                              \
    _Pragma("unroll") for (int it = 0; it < 2; ++it) {                       \
      const int seg = wave * 2 + it;                                         \
      async_copy16(ab + (size_t)(seg * 8) * KTOT + i0s + ssrc_off,           \
                   &as[buf][seg * 512]);                                     \
    }                                                                        \
    _Pragma("unroll") for (int it = 0; it < 4; ++it) {                       \
      const int seg = wave * 4 + it;                                         \
      async_copy16(bb + (size_t)(seg * 8) * KTOT + i0s + ssrc_off,           \
                   &bs[buf][seg * 512]);                                     \
    }                                                                        \
  }

  GSTAGE(0, 0);
  for (int kb = 0; kb < 27; ++kb) {
    const int cur = kb & 1;
    if (kb < 26) {
      GSTAGE(kb + 1, cur ^ 1);
      WAITV(6);          // step kb's 6 copies complete; kb+1's stay in flight
    } else {
      WAITV(0);
    }
    SBAR();              // all waves: as[cur]/bs[cur] valid

#pragma unroll
    for (int kk2 = 0; kk2 < 2; ++kk2) {
      const int jj = kk2 * 4 + quad;
      const int coff = ((jj ^ l7) << 3);
      half8 af[2], bf[4];
#pragma unroll
      for (int mt = 0; mt < 2; ++mt)
        af[mt] =
            *(const half8*)(&as[cur][(wm * 32 + mt * 16 + frow) * 64 + coff]);
#pragma unroll
      for (int nt = 0; nt < 4; ++nt)
        bf[nt] =
            *(const half8*)(&bs[cur][(wn * 64 + nt * 16 + frow) * 64 + coff]);
      // first operand = w-fragment => D row (quad*4+reg) = w, D col = o
#pragma unroll
      for (int mt = 0; mt < 2; ++mt)
#pragma unroll
        for (int nt = 0; nt < 4; ++nt)
          acc[mt][nt] = __builtin_amdgcn_mfma_f32_16x16x32_f16(
              bf[nt], af[mt], acc[mt][nt], 0, 0, 0);
    }
    SBAR();              // reads of buf cur done before kb+2's DMA reuses it
  }

  // epilogue: out[b][w][o] fp32 = bias + acc.  mt inner => 128 B contiguous
  // per (nt,r) per wave (L2 write-combine pattern).
  const int col = lane & 15;
  float* ob = out + (size_t)b * OUTW * OCH;
#pragma unroll
  for (int nt = 0; nt < 4; ++nt) {
    const int wb = wn * 64 + nt * 16 + quad * 4;
#pragma unroll
    for (int r = 0; r < 4; ++r) {
      const int w = wb + r;
#pragma unroll
      for (int mt = 0; mt < 2; ++mt) {
        const int o = o0 + wm * 32 + mt * 16 + col;
        ob[(size_t)w * OCH + o] = bias[o] + acc[mt][nt][r];
      }
    }
  }
}

// ---------------------------------------------------------------------------
extern "C" void kernel_launch(void* const* d_in, const int* in_sizes, int n_in,
                              void* d_out, int out_size, void* d_ws, size_t ws_size,
                              hipStream_t stream) {
  const float* x = (const float*)d_in[0];       // [32, 4096, 64]
  const float* weight = (const float*)d_in[1];  // [512, 576, 3]
  const float* bias = (const float*)d_in[2];    // [512]
  float* out = (float*)d_out;                   // [32, 128, 512]

  char* ws = (char*)d_ws;
  const size_t w_bytes = (size_t)OCH * KTOT * sizeof(_Float16);            // 1,769,472
  const size_t m_bytes = (size_t)BATCH * T_ROWS * ICH * sizeof(_Float16);  // 38,043,648
  _Float16* wkr = (_Float16*)ws;
  _Float16* m_ws = (_Float16*)(ws + w_bytes);
  _Float16* pm = (_Float16*)(ws + w_bytes + m_bytes);  // [32][128][1728] fp16

  hipLaunchKernelGGL(stft_wrepack_kernel, dim3(258, BATCH), dim3(256), 0,
                     stream, x, weight, m_ws, wkr);
  hipLaunchKernelGGL(pmean_kernel, dim3(OUTW, BATCH), dim3(256), 0, stream,
                     m_ws, pm);
  hipLaunchKernelGGL(gemm_pooled_kernel, dim3(256), dim3(256), 0, stream,
                     pm, wkr, bias, out);
}

// Round 16
// 114.556 us; speedup vs baseline: 1.0413x; 1.0413x over previous
//
#include <hip/hip_runtime.h>
#include <hip/hip_bf16.h>

// Problem constants
#define BATCH 32
#define LTOT 4096
#define CCH 64
#define NFFT 16
#define HOP 4
#define NF 9            // n_fft/2+1
#define T_FR 1025       // 1 + L/HOP
#define ICH 576         // C * NF
#define OCH 512
#define TY 1023         // conv output length
#define OUTW 128
#define KTOT 1728       // 3 taps x 576

typedef __attribute__((ext_vector_type(8))) _Float16 half8;
typedef __attribute__((ext_vector_type(4))) float floatx4;

// cos(n*pi/8) for n = 0..15 — used only for the window now.
__device__ constexpr float C16[16] = {
    1.0f,  0.923879533f,  0.707106781f,  0.382683432f,  0.0f, -0.382683432f,
   -0.707106781f, -0.923879533f, -1.0f, -0.923879533f, -0.707106781f,
   -0.382683432f,  0.0f,  0.382683432f,  0.707106781f,  0.923879533f};

#define C1F 0.923879533f   // cos(pi/8)
#define C2F 0.707106781f   // cos(2pi/8)
#define C3F 0.382683432f   // cos(3pi/8) = sin(pi/8)

__device__ __forceinline__ void async_copy16(const _Float16* g, _Float16* l) {
  __builtin_amdgcn_global_load_lds(
      (const __attribute__((address_space(1))) unsigned int*)g,
      (__attribute__((address_space(3))) unsigned int*)l, 16, 0, 0);
}

// R24: raw v_sqrt_f32 (~1 ulp).  sqrtf() without -ffast-math is a ~25-op
// guarded sequence.
__device__ __forceinline__ float fsqrt_fast(float v) {
  float r;
  asm("v_sqrt_f32 %0, %1" : "=v"(r) : "v"(v));
  return r;
}

// raw barrier + counted vmcnt (no compiler-inserted vmcnt(0) drain)
#define SBAR() asm volatile("s_barrier" ::: "memory")
#define WAITV(N) asm volatile("s_waitcnt vmcnt(" #N ")" ::: "memory")

// ---------------------------------------------------------------------------
// Kernel 1 (R29): STFT+pool fused, WAVE-PER-BIN structure.
// R28 measured: fused (40 us) beats split (47 us) — m_ws round-trip loses.
// R27 ledger for the fused 40 us: ~12 VALU + ~8 HBM + ~20 us STRUCTURE
// (4 barrier phases, cross-wave LDS reduction, strided epilogue, 1.37x
// recompute).  R29 removes the structure:
//   - one WAVE owns one whole w-bin (lane = channel c); walks its <=11
//     m-rows serially, acc[3][9] in registers.  No cross-wave reduction,
//     no divergent epilogue, ONE barrier.
//   - block = 4 CONSECUTIVE bins sharing one x-window stage (<=152 rows,
//     38.9 KB -> 4 blocks/CU); x recompute 1.37x -> ~1.1x.
//   - per-wave store: 27 x 128 B contiguous (k*576+f*64+c layout).
// Factored DFT + fast sqrt carried verbatim (R26 identity ledger; f=8 fold
// EVEN: re8 = wxp+(Se-So)).  Numerics == R27 (absmax 0.03125 path).
// block 256 = 64 c x 4 bins; grid (32 bin-groups, 32 b).
// ---------------------------------------------------------------------------
__global__ __launch_bounds__(256) void stft_pool_kernel(
    const float* __restrict__ x, const float* __restrict__ weight,
    _Float16* __restrict__ pm, _Float16* __restrict__ wkr) {
  const int wg = blockIdx.x;                   // bin-group 0..31
  const int b = blockIdx.y;
  const int tid = threadIdx.x;

  // ---- weight repack (grid has 262144 threads < 294912 entries: 2-pass) --
  for (int gid = (b * 32 + wg) * 256 + tid; gid < OCH * ICH;
       gid += 32 * BATCH * 256) {
    int o = gid / ICH, i = gid - o * ICH;
    int cc = i / 9, f = i - cc * 9;
    const float* src = weight + (size_t)o * (ICH * 3) + i * 3;
    _Float16* dst = wkr + (size_t)o * KTOT + f * 64 + cc;
#pragma unroll
    for (int k = 0; k < 3; ++k)
      dst[k * ICH] = (_Float16)src[k];
  }

  // ---- group geometry: bins w0..w0+3 need m rows s0 .. e3+1 ----
  const int w0 = wg * 4;
  const int s0 = (w0 * TY) >> 7;
  const int e3 = ((w0 + 4) * TY + 127) >> 7;   // one past last conv row
  const int RM = e3 + 2 - s0;                  // m rows, <= 35
  const int nrow = RM * 4 + 12;                // x rows, <= 152

  __shared__ float xs[152 * 64];               // 38.9 KB -> 4 blocks/CU

  // ---- stage x rows s0*4-8 .. (e3+1)*4+7 (reflect-padded), float4 ----
  const int l0 = s0 * 4 - 8;
  const float* xb = x + (size_t)b * LTOT * CCH;
  for (int u = tid; u < nrow * 16; u += 256) {
    int r = u >> 4, c4 = u & 15;
    int l = l0 + r;
    if (l < 0) l = -l;
    if (l >= LTOT) l = 2 * LTOT - 2 - l;
    *(floatx4*)(&xs[r * 64 + c4 * 4]) =
        *(const floatx4*)(&xb[(size_t)l * CCH + c4 * 4]);
  }
  __syncthreads();                             // the only barrier

  // ---- wave tq owns bin w0+tq; lane = channel c ----
  const int c = tid & 63, tq = tid >> 6;
  const int w = w0 + tq;
  const int s = (w * TY) >> 7;
  const int e = ((w + 1) * TY + 127) >> 7;
  const int cnt = e - s;                       // 8 or 9
  const float inv = 1.0f / (float)cnt;

  float acc[3][NF];
#pragma unroll
  for (int k = 0; k < 3; ++k)
#pragma unroll
    for (int f = 0; f < NF; ++f) acc[k][f] = 0.0f;

  for (int t = s; t <= e + 1; ++t) {           // <= 11 rows, wave-uniform
    const int rb = (t - s0) * 4;
    float wx[16];
#pragma unroll
    for (int j = 0; j < 16; ++j)
      wx[j] = xs[(rb + j) * 64 + c] * (0.5f * (1.0f - C16[j]));
    // fold j <-> 16-j
    const float s1 = wx[1] + wx[15], d1 = wx[1] - wx[15];
    const float s2 = wx[2] + wx[14], d2 = wx[2] - wx[14];
    const float s3 = wx[3] + wx[13], d3 = wx[3] - wx[13];
    const float s4 = wx[4] + wx[12], d4 = wx[4] - wx[12];
    const float s5 = wx[5] + wx[11], d5 = wx[5] - wx[11];
    const float s6 = wx[6] + wx[10], d6 = wx[6] - wx[10];
    const float s7 = wx[7] + wx[9],  d7 = wx[7] - wx[9];
    const float wxp = wx[0] + wx[8], wxm = wx[0] - wx[8];
    // shared sums
    const float u1 = s2 - s6, u2 = s1 - s7, u3 = s3 - s5;
    const float v1 = d2 + d6, v2 = d1 + d7, v3 = d3 + d5;
    const float Se = s2 + s4 + s6;
    const float So = (s1 + s3) + (s5 + s7);
    // f = 0, 8: im == 0 (even fold both use wxp)
    const float re0 = wxp + Se + So;
    const float re8 = wxp + (Se - So);
    // pair (1,7) and (3,5) share products
    const float tA = C2F * u1;
    const float A1 = wxm + tA, A3 = wxm - tA;
    const float B1 = C1F * u2 + C3F * u3;
    const float B3 = C3F * u2 - C1F * u3;
    const float tP = C2F * v1;
    const float P1 = d4 + tP, P3 = tP - d4;
    const float Q1 = C3F * v2 + C1F * v3;
    const float Q3 = C1F * v2 - C3F * v3;
    // pair (2,6)
    const float A2 = wxp - s4;
    const float B2 = C2F * (((s1 - s3) - s5) + s7);
    const float P2 = d2 - d6;
    const float Q2 = C2F * (((d1 + d3) - d5) - d7);
    // f = 4
    const float re4 = ((wxp - s2) + s4) - s6;
    const float im4 = ((d1 - d3) + d5) - d7;

    float mg[NF];
    mg[0] = fabsf(re0);
    mg[8] = fabsf(re8);
    {
      const float r1 = A1 + B1, i1 = P1 + Q1;
      mg[1] = fsqrt_fast(r1 * r1 + i1 * i1);
      const float r7 = A1 - B1, i7 = Q1 - P1;
      mg[7] = fsqrt_fast(r7 * r7 + i7 * i7);
      const float r2 = A2 + B2, i2 = P2 + Q2;
      mg[2] = fsqrt_fast(r2 * r2 + i2 * i2);
      const float r6 = A2 - B2, i6 = Q2 - P2;
      mg[6] = fsqrt_fast(r6 * r6 + i6 * i6);
      const float r3 = A3 + B3, i3 = P3 + Q3;
      mg[3] = fsqrt_fast(r3 * r3 + i3 * i3);
      const float r5 = A3 - B3, i5 = Q3 - P3;
      mg[5] = fsqrt_fast(r5 * r5 + i5 * i5);
      mg[4] = fsqrt_fast(re4 * re4 + im4 * im4);
    }
    // row t feeds tap k iff t-k in [s, e)  (wave-uniform scalar branch)
#pragma unroll
    for (int k = 0; k < 3; ++k)
      if ((unsigned)(t - k - s) < (unsigned)cnt)
#pragma unroll
        for (int f = 0; f < NF; ++f) acc[k][f] += mg[f];
  }

  // ---- store: 27 contiguous 128-B segments per wave ----
  _Float16* pmo = pm + ((size_t)b * OUTW + w) * KTOT;
#pragma unroll
  for (int k = 0; k < 3; ++k)
#pragma unroll
    for (int f = 0; f < NF; ++f)
      pmo[k * ICH + f * 64 + c] = (_Float16)(acc[k][f] * inv);
}

// ---------------------------------------------------------------------------
// Kernel 2 (R27, unchanged): the collapsed GEMM, double-buffered.
//   out[b][w][o] = bias[o] + sum_{kappa<1728} wkr[o][kappa]*pmean[b][w][kappa]
// as/bs double-buffered (48 KB), step k+1's 6 copies/wave issued BEFORE
// computing step k, raw s_barrier + counted vmcnt(6).
// Tile 64(o) x 128(w = one batch), grid 256 = 1 block/CU; proven R13
// fragment/staging swizzle.  XCD map: all 8 o-tiles of batch b on one XCD.
// ---------------------------------------------------------------------------
__global__ __launch_bounds__(256, 2) void gemm_pooled_kernel(
    const _Float16* __restrict__ pm, const _Float16* __restrict__ wkr,
    const float* __restrict__ bias, float* __restrict__ out) {
  const int lid = blockIdx.x;            // 0..255
  const int xcd = lid & 7;
  const int rest = lid >> 3;             // 0..31
  const int m8 = rest & 7;               // o-tile 0..7
  const int bq = rest >> 3;              // 0..3
  const int b = bq * 8 + xcd;
  const int o0 = m8 * 64;

  const int tid = threadIdx.x;
  const int wave = tid >> 6, lane = tid & 63;
  const int wm = wave >> 1, wn = wave & 1;   // 2(o) x 2(w) wave grid

  __shared__ _Float16 as[2][64 * 64];    // 2 x 8 KB  (W rows o0..o0+63)
  __shared__ _Float16 bs[2][128 * 64];   // 2 x 16 KB (pmean rows, all w of b)

  floatx4 acc[2][4];
#pragma unroll
  for (int mt = 0; mt < 2; ++mt)
#pragma unroll
    for (int nt = 0; nt < 4; ++nt)
      acc[mt][nt] = (floatx4)0.0f;

  const int frow = lane & 15;
  const int quad = lane >> 4;
  const int l7 = lane & 7;
  const int srow = lane >> 3;
  const int ssrc_off = srow * KTOT + (l7 ^ srow) * 8;

  const _Float16* ab = wkr + (size_t)o0 * KTOT;
  const _Float16* bb = pm + (size_t)b * OUTW * KTOT;

  // per-wave per-step vmem: 2 A copies then 4 B copies (FIFO, uniform)
#define GSTAGE(kbx, buf)                                                     \
  {                                                                          \
    const int i0s = (kbx) * 64;                                              \
    _Pragma("unroll") for (int it = 0; it < 2; ++it) {                       \
      const int seg = wave * 2 + it;                                         \
      async_copy16(ab + (size_t)(seg * 8) * KTOT + i0s + ssrc_off,           \
                   &as[buf][seg * 512]);                                     \
    }                                                                        \
    _Pragma("unroll") for (int it = 0; it < 4; ++it) {                       \
      const int seg = wave * 4 + it;                                         \
      async_copy16(bb + (size_t)(seg * 8) * KTOT + i0s + ssrc_off,           \
                   &bs[buf][seg * 512]);                                     \
    }                                                                        \
  }

  GSTAGE(0, 0);
  for (int kb = 0; kb < 27; ++kb) {
    const int cur = kb & 1;
    if (kb < 26) {
      GSTAGE(kb + 1, cur ^ 1);
      WAITV(6);          // step kb's 6 copies complete; kb+1's stay in flight
    } else {
      WAITV(0);
    }
    SBAR();              // all waves: as[cur]/bs[cur] valid

#pragma unroll
    for (int kk2 = 0; kk2 < 2; ++kk2) {
      const int jj = kk2 * 4 + quad;
      const int coff = ((jj ^ l7) << 3);
      half8 af[2], bf[4];
#pragma unroll
      for (int mt = 0; mt < 2; ++mt)
        af[mt] =
            *(const half8*)(&as[cur][(wm * 32 + mt * 16 + frow) * 64 + coff]);
#pragma unroll
      for (int nt = 0; nt < 4; ++nt)
        bf[nt] =
            *(const half8*)(&bs[cur][(wn * 64 + nt * 16 + frow) * 64 + coff]);
      // first operand = w-fragment => D row (quad*4+reg) = w, D col = o
#pragma unroll
      for (int mt = 0; mt < 2; ++mt)
#pragma unroll
        for (int nt = 0; nt < 4; ++nt)
          acc[mt][nt] = __builtin_amdgcn_mfma_f32_16x16x32_f16(
              bf[nt], af[mt], acc[mt][nt], 0, 0, 0);
    }
    SBAR();              // reads of buf cur done before kb+2's DMA reuses it
  }

  // epilogue: out[b][w][o] fp32 = bias + acc.  mt inner => 128 B contiguous
  // per (nt,r) per wave (L2 write-combine pattern).
  const int col = lane & 15;
  float* ob = out + (size_t)b * OUTW * OCH;
#pragma unroll
  for (int nt = 0; nt < 4; ++nt) {
    const int wb = wn * 64 + nt * 16 + quad * 4;
#pragma unroll
    for (int r = 0; r < 4; ++r) {
      const int w = wb + r;
#pragma unroll
      for (int mt = 0; mt < 2; ++mt) {
        const int o = o0 + wm * 32 + mt * 16 + col;
        ob[(size_t)w * OCH + o] = bias[o] + acc[mt][nt][r];
      }
    }
  }
}

// ---------------------------------------------------------------------------
extern "C" void kernel_launch(void* const* d_in, const int* in_sizes, int n_in,
                              void* d_out, int out_size, void* d_ws, size_t ws_size,
                              hipStream_t stream) {
  const float* x = (const float*)d_in[0];       // [32, 4096, 64]
  const float* weight = (const float*)d_in[1];  // [512, 576, 3]
  const float* bias = (const float*)d_in[2];    // [512]
  float* out = (float*)d_out;                   // [32, 128, 512]

  char* ws = (char*)d_ws;
  const size_t w_bytes = (size_t)OCH * KTOT * sizeof(_Float16);  // 1,769,472
  _Float16* wkr = (_Float16*)ws;
  _Float16* pm = (_Float16*)(ws + w_bytes);   // [32][128][1728] fp16, 14.2 MB

  hipLaunchKernelGGL(stft_pool_kernel, dim3(32, BATCH), dim3(256), 0,
                     stream, x, weight, pm, wkr);
  hipLaunchKernelGGL(gemm_pooled_kernel, dim3(256), dim3(256), 0, stream,
                     pm, wkr, bias, out);
}

// Round 17
// 112.725 us; speedup vs baseline: 1.0582x; 1.0162x over previous
//
#include <hip/hip_runtime.h>
#include <hip/hip_bf16.h>

// Problem constants
#define BATCH 32
#define LTOT 4096
#define CCH 64
#define NFFT 16
#define HOP 4
#define NF 9            // n_fft/2+1
#define T_FR 1025       // 1 + L/HOP
#define ICH 576         // C * NF
#define OCH 512
#define TY 1023         // conv output length
#define OUTW 128
#define KTOT 1728       // 3 taps x 576

typedef __attribute__((ext_vector_type(8))) _Float16 half8;
typedef __attribute__((ext_vector_type(4))) float floatx4;

// cos(n*pi/8) for n = 0..15 — used only for the window now.
__device__ constexpr float C16[16] = {
    1.0f,  0.923879533f,  0.707106781f,  0.382683432f,  0.0f, -0.382683432f,
   -0.707106781f, -0.923879533f, -1.0f, -0.923879533f, -0.707106781f,
   -0.382683432f,  0.0f,  0.382683432f,  0.707106781f,  0.923879533f};

#define C1F 0.923879533f   // cos(pi/8)
#define C2F 0.707106781f   // cos(2pi/8)
#define C3F 0.382683432f   // cos(3pi/8) = sin(pi/8)

__device__ __forceinline__ void async_copy16(const _Float16* g, _Float16* l) {
  __builtin_amdgcn_global_load_lds(
      (const __attribute__((address_space(1))) unsigned int*)g,
      (__attribute__((address_space(3))) unsigned int*)l, 16, 0, 0);
}

// R24: raw v_sqrt_f32 (~1 ulp).  sqrtf() without -ffast-math is a ~25-op
// guarded sequence.
__device__ __forceinline__ float fsqrt_fast(float v) {
  float r;
  asm("v_sqrt_f32 %0, %1" : "=v"(r) : "v"(v));
  return r;
}

// raw barrier + counted vmcnt (no compiler-inserted vmcnt(0) drain)
#define SBAR() asm volatile("s_barrier" ::: "memory")
#define WAITV(N) asm volatile("s_waitcnt vmcnt(" #N ")" ::: "memory")

// ---------------------------------------------------------------------------
// Kernel 1 (R27 final): STFT magnitude + bin-pool FUSED (+ weight repack).
// One block per (w-bin, b): computes m rows s..e+1 from x directly,
// accumulates per-tap bin sums in registers, reduces across waves via LDS,
// writes pm[b][w][1728] fp16.
// History: fused beats split by ~7 us (R28: m_ws round-trip loses).  R25/R26
// factored 16-pt real DFT (identity ledger in R26 notes; f=8 fold EVEN:
// re8 = wxp+(Se-So)).  R27 dropped per-magnitude fp16 round-trip.  R29's
// wave-per-bin restructure was null (+2 us) — this phase-split structure at
// 8 blocks/CU is the best measured form (~40 us; issue+pipeline floor).
// block 256 = 64 c x 4 tq; grid (128 w, 32 b); arena 14.3 KB -> 8 blocks/CU.
// ---------------------------------------------------------------------------
__global__ __launch_bounds__(256) void stft_pool_kernel(
    const float* __restrict__ x, const float* __restrict__ weight,
    _Float16* __restrict__ pm, _Float16* __restrict__ wkr) {
  const int w = blockIdx.x, b = blockIdx.y;
  const int tid = threadIdx.x;

  // ---- weight repack slice (independent; first 1152 blocks cover it) ----
  const int gid = (b * 128 + w) * 256 + tid;
  if (gid < OCH * ICH) {
    int o = gid / ICH, i = gid - o * ICH;
    int c = i / 9, f = i - c * 9;
    const float* src = weight + (size_t)o * (ICH * 3) + i * 3;
    _Float16* dst = wkr + (size_t)o * KTOT + f * 64 + c;
#pragma unroll
    for (int k = 0; k < 3; ++k)
      dst[k * ICH] = (_Float16)src[k];
  }

  // ---- bin geometry ----
  const int s = (w * TY) >> 7;                 // first conv-output row of bin
  const int e = ((w + 1) * TY + 127) >> 7;     // one past last
  const int cnt = e - s;                       // 8 or 9
  const int R = cnt + 2;                       // m rows s..e+1 (taps 0..2)
  const float inv = 1.0f / (float)cnt;

  __shared__ float arena[56 * 64];             // 14.3 KB union: xs | red
  float* xs = arena;                           // [R*4+12 <= 56][64]
  float* red = arena;                          // [2][27][64] after barrier

  // ---- stage x rows l_base .. l_base+nrow-1 (reflect-padded), float4 ----
  const int l_base = s * 4 - 8;
  const int nrow = R * 4 + 12;                 // <= 56
  const float* xb = x + (size_t)b * LTOT * CCH;
#pragma unroll
  for (int it = 0; it < 4; ++it) {
    int u = it * 256 + tid;
    int r = u >> 4, c4 = u & 15;
    if (r < nrow) {
      int l = l_base + r;
      if (l < 0) l = -l;
      if (l >= LTOT) l = 2 * LTOT - 2 - l;
      *(floatx4*)(&xs[r * 64 + c4 * 4]) =
          *(const floatx4*)(&xb[(size_t)l * CCH + c4 * 4]);
    }
  }
  __syncthreads();

  const int c = tid & 63, tq = tid >> 6;       // wave == tq

  float acc[3][NF];
#pragma unroll
  for (int k = 0; k < 3; ++k)
#pragma unroll
    for (int f = 0; f < NF; ++f) acc[k][f] = 0.0f;

  // ---- rows tq, tq+4, tq+8 ----
#pragma unroll
  for (int it = 0; it < 3; ++it) {
    const int rl = tq + it * 4;                // local m-row index
    if (rl < R) {
      float wx[16];
#pragma unroll
      for (int j = 0; j < 16; ++j)
        wx[j] = xs[(rl * 4 + j) * 64 + c] * (0.5f * (1.0f - C16[j]));
      // fold j <-> 16-j
      const float s1 = wx[1] + wx[15], d1 = wx[1] - wx[15];
      const float s2 = wx[2] + wx[14], d2 = wx[2] - wx[14];
      const float s3 = wx[3] + wx[13], d3 = wx[3] - wx[13];
      const float s4 = wx[4] + wx[12], d4 = wx[4] - wx[12];
      const float s5 = wx[5] + wx[11], d5 = wx[5] - wx[11];
      const float s6 = wx[6] + wx[10], d6 = wx[6] - wx[10];
      const float s7 = wx[7] + wx[9],  d7 = wx[7] - wx[9];
      const float wxp = wx[0] + wx[8], wxm = wx[0] - wx[8];
      // shared sums
      const float u1 = s2 - s6, u2 = s1 - s7, u3 = s3 - s5;
      const float v1 = d2 + d6, v2 = d1 + d7, v3 = d3 + d5;
      const float Se = s2 + s4 + s6;
      const float So = (s1 + s3) + (s5 + s7);
      // f = 0, 8: im == 0 (even fold both use wxp)
      const float re0 = wxp + Se + So;
      const float re8 = wxp + (Se - So);
      // pair (1,7) and (3,5) share products
      const float tA = C2F * u1;
      const float A1 = wxm + tA, A3 = wxm - tA;
      const float B1 = C1F * u2 + C3F * u3;
      const float B3 = C3F * u2 - C1F * u3;
      const float tP = C2F * v1;
      const float P1 = d4 + tP, P3 = tP - d4;
      const float Q1 = C3F * v2 + C1F * v3;
      const float Q3 = C1F * v2 - C3F * v3;
      // pair (2,6)
      const float A2 = wxp - s4;
      const float B2 = C2F * (((s1 - s3) - s5) + s7);
      const float P2 = d2 - d6;
      const float Q2 = C2F * (((d1 + d3) - d5) - d7);
      // f = 4
      const float re4 = ((wxp - s2) + s4) - s6;
      const float im4 = ((d1 - d3) + d5) - d7;

      float mg[NF];
      mg[0] = fabsf(re0);
      mg[8] = fabsf(re8);
      {
        const float r1 = A1 + B1, i1 = P1 + Q1;
        mg[1] = fsqrt_fast(r1 * r1 + i1 * i1);
        const float r7 = A1 - B1, i7 = Q1 - P1;
        mg[7] = fsqrt_fast(r7 * r7 + i7 * i7);
        const float r2 = A2 + B2, i2 = P2 + Q2;
        mg[2] = fsqrt_fast(r2 * r2 + i2 * i2);
        const float r6 = A2 - B2, i6 = Q2 - P2;
        mg[6] = fsqrt_fast(r6 * r6 + i6 * i6);
        const float r3 = A3 + B3, i3 = P3 + Q3;
        mg[3] = fsqrt_fast(r3 * r3 + i3 * i3);
        const float r5 = A3 - B3, i5 = Q3 - P3;
        mg[5] = fsqrt_fast(r5 * r5 + i5 * i5);
        mg[4] = fsqrt_fast(re4 * re4 + im4 * im4);
      }
      // row rl contributes to tap k iff rl-k in [0, cnt); rl, cnt are
      // wave-uniform -> scalar branches, only taken adds cost VALU.
#pragma unroll
      for (int k = 0; k < 3; ++k)
        if ((unsigned)(rl - k) < (unsigned)cnt)
#pragma unroll
          for (int f = 0; f < NF; ++f) acc[k][f] += mg[f];
    }
  }

  __syncthreads();   // xs dead; arena becomes red[2][27][64]

  // ---- two-stage cross-wave reduction ----
  if (tq < 2) {
#pragma unroll
    for (int k = 0; k < 3; ++k)
#pragma unroll
      for (int f = 0; f < NF; ++f)
        red[((tq * 27) + k * 9 + f) * 64 + c] = acc[k][f];
  }
  __syncthreads();
  if (tq >= 2) {
#pragma unroll
    for (int k = 0; k < 3; ++k)
#pragma unroll
      for (int f = 0; f < NF; ++f) {
        const int idx = (((tq - 2) * 27) + k * 9 + f) * 64 + c;
        red[idx] += acc[k][f];
      }
  }
  __syncthreads();

  // ---- reduce 2 slots, mean, fp16, store pm[b][w][kappa] ----
  _Float16* pmo = pm + ((size_t)b * OUTW + w) * KTOT;
  for (int j = tid; j < KTOT; j += 256) {
    const int k = j / ICH;
    const int rem = j - k * ICH;
    const int f = rem >> 6;                    // kappa = k*576 + f*64 + c
    const int cc = rem & 63;
    const int base = (k * 9 + f) * 64 + cc;
    const float sum = red[base] + red[27 * 64 + base];
    pmo[j] = (_Float16)(sum * inv);
  }
}

// ---------------------------------------------------------------------------
// Kernel 2 (R27 final): the collapsed GEMM, double-buffered.
//   out[b][w][o] = bias[o] + sum_{kappa<1728} wkr[o][kappa]*pmean[b][w][kappa]
// as/bs double-buffered (48 KB), step k+1's 6 copies/wave issued BEFORE
// computing step k, raw s_barrier + counted vmcnt(6) (per-wave counts
// uniform: 2 A + 4 B; FIFO -> wait 6 = all of step k's complete).
// Tile 64(o) x 128(w = one batch), grid 256 = 1 block/CU; proven R13
// fragment/staging swizzle.  XCD map: all 8 o-tiles of batch b on one XCD.
// ---------------------------------------------------------------------------
__global__ __launch_bounds__(256, 2) void gemm_pooled_kernel(
    const _Float16* __restrict__ pm, const _Float16* __restrict__ wkr,
    const float* __restrict__ bias, float* __restrict__ out) {
  const int lid = blockIdx.x;            // 0..255
  const int xcd = lid & 7;
  const int rest = lid >> 3;             // 0..31
  const int m8 = rest & 7;               // o-tile 0..7
  const int bq = rest >> 3;              // 0..3
  const int b = bq * 8 + xcd;
  const int o0 = m8 * 64;

  const int tid = threadIdx.x;
  const int wave = tid >> 6, lane = tid & 63;
  const int wm = wave >> 1, wn = wave & 1;   // 2(o) x 2(w) wave grid

  __shared__ _Float16 as[2][64 * 64];    // 2 x 8 KB  (W rows o0..o0+63)
  __shared__ _Float16 bs[2][128 * 64];   // 2 x 16 KB (pmean rows, all w of b)

  floatx4 acc[2][4];
#pragma unroll
  for (int mt = 0; mt < 2; ++mt)
#pragma unroll
    for (int nt = 0; nt < 4; ++nt)
      acc[mt][nt] = (floatx4)0.0f;

  const int frow = lane & 15;
  const int quad = lane >> 4;
  const int l7 = lane & 7;
  const int srow = lane >> 3;
  const int ssrc_off = srow * KTOT + (l7 ^ srow) * 8;

  const _Float16* ab = wkr + (size_t)o0 * KTOT;
  const _Float16* bb = pm + (size_t)b * OUTW * KTOT;

  // per-wave per-step vmem: 2 A copies then 4 B copies (FIFO, uniform)
#define GSTAGE(kbx, buf)                                                     \
  {                                                                          \
    const int i0s = (kbx) * 64;                                              \
    _Pragma("unroll") for (int it = 0; it < 2; ++it) {                       \
      const int seg = wave * 2 + it;                                         \
      async_copy16(ab + (size_t)(seg * 8) * KTOT + i0s + ssrc_off,           \
                   &as[buf][seg * 512]);                                     \
    }                                                                        \
    _Pragma("unroll") for (int it = 0; it < 4; ++it) {                       \
      const int seg = wave * 4 + it;                                         \
      async_copy16(bb + (size_t)(seg * 8) * KTOT + i0s + ssrc_off,           \
                   &bs[buf][seg * 512]);                                     \
    }                                                                        \
  }

  GSTAGE(0, 0);
  for (int kb = 0; kb < 27; ++kb) {
    const int cur = kb & 1;
    if (kb < 26) {
      GSTAGE(kb + 1, cur ^ 1);
      WAITV(6);          // step kb's 6 copies complete; kb+1's stay in flight
    } else {
      WAITV(0);
    }
    SBAR();              // all waves: as[cur]/bs[cur] valid

#pragma unroll
    for (int kk2 = 0; kk2 < 2; ++kk2) {
      const int jj = kk2 * 4 + quad;
      const int coff = ((jj ^ l7) << 3);
      half8 af[2], bf[4];
#pragma unroll
      for (int mt = 0; mt < 2; ++mt)
        af[mt] =
            *(const half8*)(&as[cur][(wm * 32 + mt * 16 + frow) * 64 + coff]);
#pragma unroll
      for (int nt = 0; nt < 4; ++nt)
        bf[nt] =
            *(const half8*)(&bs[cur][(wn * 64 + nt * 16 + frow) * 64 + coff]);
      // first operand = w-fragment => D row (quad*4+reg) = w, D col = o
#pragma unroll
      for (int mt = 0; mt < 2; ++mt)
#pragma unroll
        for (int nt = 0; nt < 4; ++nt)
          acc[mt][nt] = __builtin_amdgcn_mfma_f32_16x16x32_f16(
              bf[nt], af[mt], acc[mt][nt], 0, 0, 0);
    }
    SBAR();              // reads of buf cur done before kb+2's DMA reuses it
  }

  // epilogue: out[b][w][o] fp32 = bias + acc.  mt inner => 128 B contiguous
  // per (nt,r) per wave (L2 write-combine pattern).
  const int col = lane & 15;
  float* ob = out + (size_t)b * OUTW * OCH;
#pragma unroll
  for (int nt = 0; nt < 4; ++nt) {
    const int wb = wn * 64 + nt * 16 + quad * 4;
#pragma unroll
    for (int r = 0; r < 4; ++r) {
      const int w = wb + r;
#pragma unroll
      for (int mt = 0; mt < 2; ++mt) {
        const int o = o0 + wm * 32 + mt * 16 + col;
        ob[(size_t)w * OCH + o] = bias[o] + acc[mt][nt][r];
      }
    }
  }
}

// ---------------------------------------------------------------------------
extern "C" void kernel_launch(void* const* d_in, const int* in_sizes, int n_in,
                              void* d_out, int out_size, void* d_ws, size_t ws_size,
                              hipStream_t stream) {
  const float* x = (const float*)d_in[0];       // [32, 4096, 64]
  const float* weight = (const float*)d_in[1];  // [512, 576, 3]
  const float* bias = (const float*)d_in[2];    // [512]
  float* out = (float*)d_out;                   // [32, 128, 512]

  char* ws = (char*)d_ws;
  const size_t w_bytes = (size_t)OCH * KTOT * sizeof(_Float16);  // 1,769,472
  _Float16* wkr = (_Float16*)ws;
  _Float16* pm = (_Float16*)(ws + w_bytes);   // [32][128][1728] fp16, 14.2 MB

  hipLaunchKernelGGL(stft_pool_kernel, dim3(OUTW, BATCH), dim3(256), 0,
                     stream, x, weight, pm, wkr);
  hipLaunchKernelGGL(gemm_pooled_kernel, dim3(256), dim3(256), 0, stream,
                     pm, wkr, bias, out);
}